// Round 3
// baseline (1059.940 us; speedup 1.0000x reference)
//
#include <hip/hip_runtime.h>
#include <stdint.h>

// TGN recommender fused pipeline — fp16 MFMA variant.
// Sizes (fixed by the problem):
#define BATCH   262144
#define DMEM    100       // memory dim
#define AS      456       // LDS A row stride (elements): 448 used + 8 pad (2-way-free banks)

typedef float    f32x4 __attribute__((ext_vector_type(4)));
typedef _Float16 f16x8 __attribute__((ext_vector_type(8)));

__device__ __forceinline__ unsigned short f2h(float f) {
  union { _Float16 h; unsigned short u; } v; v.h = (_Float16)f;  // RNE
  return v.u;
}
__device__ __forceinline__ float h2f(unsigned short u) {
  union { _Float16 h; unsigned short u; } v; v.u = u; return (float)v.h;
}

// ---------------------------------------------------------------------------
// Prep: pack weights into MFMA B-operand fragment order (fp16).
// Main GEMM op list (270 ops), A columns: [0:304)=x (src|dst|msg|t_enc),
// [304:320)=0, [320:420)=h, [420:448)=0.
//   phase1: kc 0..9  (K 0:320),  nt 0..18 (cols 0:304)  -> W_ih[col][k]
//   phase2: kc 10..13 (K 320:448), nt 0..12 (cols 0:208) -> W_hh[col][k-320], col<200
//   phase3: kc 10..13,            nt 19..25 (cols 304:416)-> W_hh[200+(col-304)][k-320]
// op index: o<190: kc=o/19, nt=o%19 ; else o2=o-190: kc=10+o2/20, p=o2%20,
//           nt = p<13 ? p : p+6.
// W1 ops (16): kc 0..3 (K=128 over h_new), nt 0..3 (64 cols).
// B-fragment layout for v_mfma_f32_16x16x32_f16: lane holds B[k][n],
// n=lane&15, k=(lane>>4)*8+j  -> frag[o][lane][j].
// ---------------------------------------------------------------------------
__global__ void prep_kernel(const float* __restrict__ W_ih, const float* __restrict__ W_hh,
                            const float* __restrict__ W1,
                            const float* __restrict__ b_ih, const float* __restrict__ b_hh,
                            unsigned short* __restrict__ Bfrag,
                            unsigned short* __restrict__ W1frag,
                            float* __restrict__ biasbuf) {
  int blk = blockIdx.x;
  int tid = threadIdx.x;
  if (blk == 72) {                       // fused biases
    if (tid < 100) {
      biasbuf[tid]       = b_ih[tid]       + b_hh[tid];        // r
      biasbuf[100 + tid] = b_ih[100 + tid] + b_hh[100 + tid];  // z
      biasbuf[200 + tid] = b_ih[200 + tid];                    // i_n
      biasbuf[300 + tid] = b_hh[200 + tid];                    // h_n
    }
    return;
  }
  int o = blk * 4 + (tid >> 6);
  if (o >= 286) return;
  int lane = tid & 63, quad = lane >> 4, l15 = lane & 15;
  if (o < 270) {
    int kc, nt;
    if (o < 190) { kc = o / 19; nt = o % 19; }
    else { int o2 = o - 190; kc = 10 + o2 / 20; int p = o2 % 20; nt = (p < 13) ? p : p + 6; }
    int col = nt * 16 + l15;
    unsigned short* dst = Bfrag + (size_t)o * 512 + lane * 8;
    for (int j = 0; j < 8; ++j) {
      int kg = kc * 32 + quad * 8 + j;
      float v = 0.f;
      if (kc < 10) {
        if (kg < 304 && col < 300) v = W_ih[col * 304 + kg];
      } else {
        int kl = kg - 320;
        if (nt < 13) { if (kl < 100 && col < 200) v = W_hh[col * 100 + kl]; }
        else { int hd = col - 304; if (kl < 100 && hd < 100) v = W_hh[(200 + hd) * 100 + kl]; }
      }
      dst[j] = f2h(v);
    }
  } else {
    int o1 = o - 270;
    int kc = o1 >> 2, nt = o1 & 3;
    int col = nt * 16 + l15;
    unsigned short* dst = W1frag + (size_t)o1 * 512 + lane * 8;
    for (int j = 0; j < 8; ++j) {
      int kg = kc * 32 + quad * 8 + j;
      dst[j] = f2h((kg < 100) ? W1[col * 100 + kg] : 0.f);
    }
  }
}

// ---------------------------------------------------------------------------
// Main fused kernel: 64 rows/block, 256 threads (4 waves: wi=row-half, wj=nt-parity).
// LDS 79.4 KB total -> 2 blocks/CU so gathers of block i+1 overlap MFMA of block i.
// ---------------------------------------------------------------------------
__global__ __launch_bounds__(256, 2)
void main_kernel(const int* __restrict__ n_id, const float* __restrict__ memory,
                 const int* __restrict__ last_update,
                 const int* __restrict__ store_src, const int* __restrict__ store_dst,
                 const int* __restrict__ store_t, const float* __restrict__ store_msg,
                 const float* __restrict__ time_w, const float* __restrict__ time_b,
                 const float* __restrict__ b1,
                 const unsigned short* __restrict__ Bfrag,
                 const unsigned short* __restrict__ W1frag,
                 const float* __restrict__ biasbuf,
                 unsigned short* __restrict__ a_ws, float* __restrict__ stats_g) {
  __shared__ __align__(16) unsigned short A_lds[64 * AS];  // 58368 B
  __shared__ uint4 Bsec[20 * 64];                          // 20480 B (also reused as hbuf)
  __shared__ float stats[128];                             // 512 B

  const int tid  = threadIdx.x;
  const int wave = tid >> 6;
  const int lane = tid & 63;
  const int quad = lane >> 4;
  const int l15  = lane & 15;
  const int wi   = wave >> 1;   // 0/1: rows [32wi, 32wi+32)
  const int wj   = wave & 1;    // nt parity
  const int blk  = blockIdx.x;

  if (tid < 128) stats[tid] = 0.f;

  // ---- stage A tile: gathers + time encoding, fp16 into LDS ----
  {
    int r = tid >> 2;           // row 0..63
    int p = tid & 3;            // quarter 0..3
    int b = blk * 64 + r;
    int n = n_id[b];
    int sidx = store_src[n];
    int didx = store_dst[n];
    float dtf = (float)(store_t[n] - last_update[n]);
    const float* ms = memory + (size_t)sidx * DMEM;
    const float* md = memory + (size_t)didx * DMEM;
    const float* mh = memory + (size_t)n * DMEM;
    unsigned short* Ar = A_lds + r * AS;
    int d0 = p * 25;
    for (int i = 0; i < 25; ++i) {
      int d = d0 + i;
      Ar[d]       = f2h(ms[d]);                                  // x: memory[src]
      Ar[100 + d] = f2h(md[d]);                                  // x: memory[dst]
      Ar[320 + d] = f2h(mh[d]);                                  // h
      Ar[204 + d] = f2h(cosf(dtf * time_w[d] + time_b[d]));      // t_enc
    }
    if (p == 0) {
      const float* mg = store_msg + (size_t)n * 4;
      for (int i = 0; i < 4; ++i)  Ar[200 + i] = f2h(mg[i]);     // raw_msg
      for (int i = 0; i < 16; ++i) Ar[304 + i] = 0;              // pad
    } else {
      int z0 = 420 + (p - 1) * 10;
      int zc = (p == 3) ? 8 : 10;
      for (int i = 0; i < zc; ++i) Ar[z0 + i] = 0;               // pad
    }
  }

  f32x4 acc[13][2];
  #pragma unroll
  for (int t = 0; t < 13; ++t)
    for (int m = 0; m < 2; ++m) acc[t][m] = f32x4{0.f, 0.f, 0.f, 0.f};

  // ---- main GEMM: 14 K-chunks of 32 ----
  for (int kc = 0; kc < 14; ++kc) {
    const int cnt    = (kc < 10) ? 19 : 20;
    const int opbase = (kc < 10) ? kc * 19 : 190 + (kc - 10) * 20;
    __syncthreads();                                   // prev B section consumed / A staged
    for (int i = 0; i < 5; ++i) {                      // stage this kc's B ops
      int ol = wave + i * 4;                           // wave-uniform predicate
      if (ol < cnt) {
        const unsigned short* g = Bfrag + (size_t)(opbase + ol) * 512 + lane * 8;
        __builtin_amdgcn_global_load_lds(
            (const __attribute__((address_space(1))) unsigned int*)g,
            (__attribute__((address_space(3))) unsigned int*)(&Bsec[ol * 64]),
            16, 0, 0);
      }
    }
    __syncthreads();
    const int kb = kc * 32 + quad * 8;
    f16x8 af0 = __builtin_bit_cast(f16x8, *(const uint4*)(A_lds + (wi * 32 + l15) * AS + kb));
    f16x8 af1 = __builtin_bit_cast(f16x8, *(const uint4*)(A_lds + (wi * 32 + 16 + l15) * AS + kb));
    if (kc < 10) {
      #pragma unroll
      for (int p = 0; p < 19; ++p) {
        if ((p & 1) != wj) continue;                   // wave-uniform
        f16x8 bfr = __builtin_bit_cast(f16x8, Bsec[p * 64 + lane]);
        int tl = p >> 1;
        acc[tl][0] = __builtin_amdgcn_mfma_f32_16x16x32_f16(af0, bfr, acc[tl][0], 0, 0, 0);
        acc[tl][1] = __builtin_amdgcn_mfma_f32_16x16x32_f16(af1, bfr, acc[tl][1], 0, 0, 0);
      }
    } else {
      #pragma unroll
      for (int p = 0; p < 20; ++p) {
        int nt = (p < 13) ? p : p + 6;
        if ((nt & 1) != wj) continue;
        f16x8 bfr = __builtin_bit_cast(f16x8, Bsec[p * 64 + lane]);
        int tl = nt >> 1;
        acc[tl][0] = __builtin_amdgcn_mfma_f32_16x16x32_f16(af0, bfr, acc[tl][0], 0, 0, 0);
        acc[tl][1] = __builtin_amdgcn_mfma_f32_16x16x32_f16(af1, bfr, acc[tl][1], 0, 0, 0);
      }
    }
  }
  __syncthreads();

  // ---- copy h (A cols 320:420) into Bsec region before gates overwrite A ----
  unsigned short* hbuf = (unsigned short*)Bsec;        // 64*100 fp16 = 12.8 KB
  for (int i = 0; i < 25; ++i) {
    int e = tid + 256 * i;                             // 0..6399
    hbuf[e] = A_lds[(e / 100) * AS + 320 + (e % 100)];
  }
  __syncthreads();

  // ---- dump accumulators (pre-activation gates) to LDS as fp16 ----
  #pragma unroll
  for (int t = 0; t < 13; ++t) {
    int col = (t * 2 + wj) * 16 + l15;                 // < 416
    #pragma unroll
    for (int m = 0; m < 2; ++m) {
      int rbase = wi * 32 + m * 16 + quad * 4;
      #pragma unroll
      for (int rr = 0; rr < 4; ++rr)
        A_lds[(rbase + rr) * AS + col] = f2h(acc[t][m][rr]);
    }
  }
  __syncthreads();

  // ---- GRU gates -> h_new (fp16, into cols 0:100) ----
  // NOTE: cols 100..127 are intentionally NOT zeroed for the W1 GEMM: W1frag
  // has exact 0.0 weights for kg>=100, so stale (finite) preacts contribute
  // 0*v = 0. A zeroing loop here previously RACED with the Gr[100+d] reads
  // of slower waves in this same barrier epoch (the round-1/2 absmax ~0.2 bug).
  for (int i = 0; i < 25; ++i) {
    int e = tid + 256 * i;
    int r = e / 100, d = e % 100;
    const unsigned short* Gr = A_lds + r * AS;
    float s_r = h2f(Gr[d])       + biasbuf[d];
    float s_z = h2f(Gr[100 + d]) + biasbuf[100 + d];
    float i_n = h2f(Gr[200 + d]) + biasbuf[200 + d];
    float h_n = h2f(Gr[304 + d]) + biasbuf[300 + d];
    float h   = h2f(hbuf[r * 100 + d]);
    float rg = 1.f / (1.f + __expf(-s_r));
    float zg = 1.f / (1.f + __expf(-s_z));
    float nn = tanhf(i_n + rg * h_n);
    float hw = (1.f - zg) * nn + zg * h;
    A_lds[r * AS + d] = f2h(hw);
  }
  __syncthreads();

  // ---- a = relu(h_new @ W1^T + b1): K=128 (4 kc), N=64 (wave takes 2 nt) ----
  f32x4 aacc[2][2];
  #pragma unroll
  for (int m = 0; m < 2; ++m)
    for (int t = 0; t < 2; ++t) aacc[m][t] = f32x4{0.f, 0.f, 0.f, 0.f};
  for (int k4 = 0; k4 < 4; ++k4) {
    int kb = k4 * 32 + quad * 8;
    f16x8 a0 = __builtin_bit_cast(f16x8, *(const uint4*)(A_lds + (wi * 32 + l15) * AS + kb));
    f16x8 a1 = __builtin_bit_cast(f16x8, *(const uint4*)(A_lds + (wi * 32 + 16 + l15) * AS + kb));
    #pragma unroll
    for (int t = 0; t < 2; ++t) {
      int nt = wj * 2 + t;
      f16x8 bfr = __builtin_bit_cast(f16x8,
          *(const uint4*)(W1frag + (size_t)(k4 * 4 + nt) * 512 + lane * 8));
      aacc[0][t] = __builtin_amdgcn_mfma_f32_16x16x32_f16(a0, bfr, aacc[0][t], 0, 0, 0);
      aacc[1][t] = __builtin_amdgcn_mfma_f32_16x16x32_f16(a1, bfr, aacc[1][t], 0, 0, 0);
    }
  }

  // ---- +b1, relu, BN partial stats, store a (fp16) ----
  float ssum[2] = {0.f, 0.f}, ssq[2] = {0.f, 0.f};
  #pragma unroll
  for (int t = 0; t < 2; ++t) {
    int col = (wj * 2 + t) * 16 + l15;
    float bb = b1[col];
    #pragma unroll
    for (int m = 0; m < 2; ++m) {
      int rbase = wi * 32 + m * 16 + quad * 4;
      #pragma unroll
      for (int rr = 0; rr < 4; ++rr) {
        float v = fmaxf(aacc[m][t][rr] + bb, 0.f);
        ssum[t] += v; ssq[t] += v * v;
        a_ws[(size_t)(blk * 64 + rbase + rr) * 64 + col] = f2h(v);
      }
    }
  }
  #pragma unroll
  for (int t = 0; t < 2; ++t) {
    ssum[t] += __shfl_xor(ssum[t], 16); ssum[t] += __shfl_xor(ssum[t], 32);
    ssq[t]  += __shfl_xor(ssq[t], 16);  ssq[t]  += __shfl_xor(ssq[t], 32);
  }
  if (quad == 0) {
    #pragma unroll
    for (int t = 0; t < 2; ++t) {
      int col = (wj * 2 + t) * 16 + l15;
      atomicAdd(&stats[col], ssum[t]);
      atomicAdd(&stats[64 + col], ssq[t]);
    }
  }
  __syncthreads();
  if (tid < 128) atomicAdd(&stats_g[tid], stats[tid]);   // one atomic/channel/block
}

// ---------------------------------------------------------------------------
// Output: fold BN (mu, var, gamma, beta) + W2/b2 into out = a.w_c + C_c.
// ---------------------------------------------------------------------------
__global__ __launch_bounds__(256)
void out_kernel(const unsigned short* __restrict__ a_ws, const float* __restrict__ stats_g,
                const float* __restrict__ gamma, const float* __restrict__ beta,
                const float* __restrict__ W2, const float* __restrict__ b2,
                float* __restrict__ out) {
  __shared__ float w0[64], w1[64], cpart[128];
  __shared__ float C0s, C1s;
  int tid = threadIdx.x;
  if (tid < 64) {
    const float invB = 1.f / (float)BATCH;
    float mu  = stats_g[tid] * invB;
    float var = stats_g[64 + tid] * invB - mu * mu;
    float g   = gamma[tid] * rsqrtf(var + 1e-5f);
    w0[tid] = g * W2[tid];
    w1[tid] = g * W2[64 + tid];
    float t = beta[tid] - mu * g;
    cpart[tid]      = t * W2[tid];
    cpart[64 + tid] = t * W2[64 + tid];
  }
  __syncthreads();
  if (tid == 0) {
    float c0 = b2[0], c1 = b2[1];
    for (int j = 0; j < 64; ++j) { c0 += cpart[j]; c1 += cpart[64 + j]; }
    C0s = c0; C1s = c1;
  }
  __syncthreads();
  int b = blockIdx.x * 256 + tid;
  const uint4* ap = (const uint4*)(a_ws + (size_t)b * 64);
  float o0 = C0s, o1 = C1s;
  #pragma unroll
  for (int i = 0; i < 8; ++i) {
    uint4 v = ap[i];
    unsigned int uu[4] = {v.x, v.y, v.z, v.w};
    #pragma unroll
    for (int q = 0; q < 4; ++q) {
      float lo = h2f((unsigned short)(uu[q] & 0xffffu));
      float hi = h2f((unsigned short)(uu[q] >> 16));
      int j = i * 8 + q * 2;
      o0 += lo * w0[j] + hi * w0[j + 1];
      o1 += lo * w1[j] + hi * w1[j + 1];
    }
  }
  *(float2*)(out + (size_t)b * 2) = make_float2(o0, o1);
}

// ---------------------------------------------------------------------------
extern "C" void kernel_launch(void* const* d_in, const int* in_sizes, int n_in,
                              void* d_out, int out_size, void* d_ws, size_t ws_size,
                              hipStream_t stream) {
  const int*   n_id   = (const int*)d_in[0];
  const float* memory = (const float*)d_in[1];
  const int*   last_u = (const int*)d_in[2];
  const int*   s_src  = (const int*)d_in[3];
  const int*   s_dst  = (const int*)d_in[4];
  const int*   s_t    = (const int*)d_in[5];
  const float* s_msg  = (const float*)d_in[6];
  const float* time_w = (const float*)d_in[7];
  const float* time_b = (const float*)d_in[8];
  const float* W_ih   = (const float*)d_in[9];
  const float* b_ih   = (const float*)d_in[10];
  const float* W_hh   = (const float*)d_in[11];
  const float* b_hh   = (const float*)d_in[12];
  const float* W1     = (const float*)d_in[13];
  const float* b1     = (const float*)d_in[14];
  const float* gamma  = (const float*)d_in[15];
  const float* beta   = (const float*)d_in[16];
  const float* W2     = (const float*)d_in[17];
  const float* b2     = (const float*)d_in[18];

  char* ws = (char*)d_ws;
  float*          stats_g = (float*)ws;                                   // 512 B
  float*          biasbuf = (float*)(ws + 512);                           // 1600 B
  unsigned short* Bfrag   = (unsigned short*)(ws + 4096);                 // 270 KiB
  unsigned short* W1frag  = (unsigned short*)(ws + 4096 + 276480);        // 16 KiB
  unsigned short* a_ws    = (unsigned short*)(ws + (1u << 20));           // 32 MiB

  hipMemsetAsync(stats_g, 0, 512, stream);
  prep_kernel<<<73, 256, 0, stream>>>(W_ih, W_hh, W1, b_ih, b_hh, Bfrag, W1frag, biasbuf);
  main_kernel<<<4096, 256, 0, stream>>>(n_id, memory, last_u, s_src, s_dst, s_t,
                                        s_msg, time_w, time_b, b1,
                                        Bfrag, W1frag, biasbuf, a_ws, stats_g);
  out_kernel<<<1024, 256, 0, stream>>>(a_ws, stats_g, gamma, beta, W2, b2, (float*)d_out);
}